// Round 7
// baseline (3053.613 us; speedup 1.0000x reference)
//
#include <hip/hip_runtime.h>
#include <math.h>

#define BATCH  65536
#define SD     256
#define AD     129
#define HID    256
#define NSTEP  30
#define EPS_LN 1e-5f

typedef _Float16 v8h  __attribute__((ext_vector_type(8)));
typedef _Float16 v2h  __attribute__((ext_vector_type(2)));
typedef float    v16f __attribute__((ext_vector_type(16)));

#define LOSCALE 4096.0f
#define LOINV   (1.0f/4096.0f)
#define MFMA(a,b,c) __builtin_amdgcn_mfma_f32_32x32x16_f16(a,b,c,0,0,0)

// d_ws layout: fragment-packed, fully-coalesced weights.
// packed[cg][t][h][ln][j] = split_h( W[k = 16t + 8*(ln>>5) + j][n = 32cg + (ln&31)] )
#define T1P_OFF 0        // 8 cg * 26 t * 2 * 64 * 16B = 425984
#define T2P_OFF 425984   // 8 cg * 16 t * 2 * 64 * 16B = 262144
#define T3P_OFF 688128   // 4 cg * 16 t * 2 * 64 * 16B = 131072
#define W3C_OFF 819200   // 256 floats (W3 col 128)

__global__ __launch_bounds__(128)
void repack(const float* __restrict__ W1, const float* __restrict__ W2,
            const float* __restrict__ W3, char* __restrict__ ws)
{
    const int b   = blockIdx.x;
    const int tid = threadIdx.x;
    if (b == 400) {   // W3 column 128 -> f32 table
        float* w3c = (float*)(ws + W3C_OFF);
        w3c[tid]       = W3[(size_t)tid * AD + 128];
        w3c[tid + 128] = W3[(size_t)(tid + 128) * AD + 128];
        return;
    }
    const int h = tid >> 6, ln = tid & 63;
    const int lh = ln >> 5, l31 = ln & 31;
    const float* W; _Float16* dst; int cg, t, K, ldw, nt;
    if (b < 208)      { cg = b / 26;         t = b % 26;         W = W1; dst = (_Float16*)(ws + T1P_OFF); K = 386; ldw = HID; nt = 26; }
    else if (b < 336) { cg = (b - 208) / 16; t = (b - 208) % 16; W = W2; dst = (_Float16*)(ws + T2P_OFF); K = 256; ldw = HID; nt = 16; }
    else              { cg = (b - 336) / 16; t = (b - 336) % 16; W = W3; dst = (_Float16*)(ws + T3P_OFF); K = 256; ldw = AD;  nt = 16; }
    const int n = 32 * cg + l31;
    _Float16 frag[8];
    #pragma unroll
    for (int j = 0; j < 8; ++j) {
        int k = 16 * t + 8 * lh + j;
        float v = (k < K) ? W[(size_t)k * ldw + n] : 0.f;
        _Float16 hi = (_Float16)v;
        frag[j] = h ? (_Float16)((v - (float)hi) * LOSCALE) : hi;
    }
    *(v8h*)(dst + ((size_t)((cg * nt + t) * 2 + h) * 64 + ln) * 8) = *(v8h*)frag;
}

__device__ __forceinline__ v16f vzero() {
    v16f z;
    #pragma unroll
    for (int i = 0; i < 16; ++i) z[i] = 0.f;
    return z;
}
// DPP butterfly pieces: quad xor1, quad xor2, row_ror:4, row_ror:8 -> 16-lane allreduce
template<int CTRL>
__device__ __forceinline__ float dppadd(float x) {
    union { float f; int i; } a, b;
    a.f = x;
    b.i = __builtin_amdgcn_update_dpp(0, a.i, CTRL, 0xF, 0xF, false);
    return x + b.f;
}
__device__ __forceinline__ float allred16(float x) {
    x = dppadd<0xB1>(x);    // quad_perm [1,0,3,2]  (xor 1)
    x = dppadd<0x4E>(x);    // quad_perm [2,3,0,1]  (xor 2)
    x = dppadd<0x124>(x);   // row_ror:4
    x = dppadd<0x128>(x);   // row_ror:8
    return x;
}
template<int N> __device__ __forceinline__ void wr_add(float* v) {
    #pragma unroll
    for (int d = 1; d < 64; d <<= 1) {
        #pragma unroll
        for (int r = 0; r < N; ++r) v[r] += __shfl_xor(v[r], d);
    }
}
template<int N> __device__ __forceinline__ void wr_max(float* v) {
    #pragma unroll
    for (int d = 1; d < 64; d <<= 1) {
        #pragma unroll
        for (int r = 0; r < N; ++r) v[r] = fmaxf(v[r], __shfl_xor(v[r], d));
    }
}
template<int N> __device__ __forceinline__ void wr_mini(int* v) {
    #pragma unroll
    for (int d = 1; d < 64; d <<= 1) {
        #pragma unroll
        for (int r = 0; r < N; ++r) v[r] = min(v[r], __shfl_xor(v[r], d));
    }
}

// Direct-load single-tile GEMM, TWO accumulators (c1 main, c2 = both corrections).
// unroll 2: TLP (4 waves/SIMD) replaces per-wave ILP; keeps staging registers low.
template<int NTILE>
__device__ __forceinline__ void gemm1(const v8h* __restrict__ P, int tbase,
    const int* __restrict__ Ab, int a0, int loff,
    v16f& c1, v16f& c2)
{
    #pragma unroll 2
    for (int t = 0; t < NTILE; ++t) {
        v8h bh = P[(size_t)(2 * (tbase + t)) * 64];
        v8h bl = P[(size_t)(2 * (tbase + t) + 1) * 64];
        v8h ah = *(const v8h*)(Ab + a0 + 8 * t);
        v8h al = *(const v8h*)(Ab + a0 + loff + 8 * t);
        c1 = MFMA(ah, bh, c1);
        c2 = MFMA(ah, bl, c2);
        c2 = MFMA(al, bh, c2);
    }
}

// M=32 rows/block, 512 threads = 8 waves, LDS ~57.9 KB -> 2 blocks/CU target.
// Register budget: __launch_bounds__(512,4) => 128 total/wave = 32 acc + ~96 VGPR.
// Layers 1/2: wave w owns all 32 rows x cols [32w, 32w+32).
// Layer 3: waves 0..3 own cols [32w, 32w+32); waves 4..7 do col 128 + t col concurrently.
__global__ __launch_bounds__(512, 4)
void actor_kernel(const float* __restrict__ state,
                  const float* __restrict__ amask,
                  const float* __restrict__ x_init,
                  const float* __restrict__ gum,
                  const float* __restrict__ b1,
                  const float* __restrict__ g1,
                  const float* __restrict__ be1,
                  const float* __restrict__ b2,
                  const float* __restrict__ g2,
                  const float* __restrict__ be2,
                  const float* __restrict__ b3,
                  const _Float16* __restrict__ T1p,
                  const _Float16* __restrict__ T2p,
                  const _Float16* __restrict__ T3p,
                  const float* __restrict__ w3cg,
                  float* __restrict__ out)
{
    __shared__ int    hA[32 * 268];             // 34.3 KB
    __shared__ int    xA[32 * 148];             // 18.9 KB
    __shared__ float2 lnp[8][2][32];            // 4 KB: per-wave 16-lane partials
    __shared__ __align__(16) float2 lnstat[32]; // 0.25 KB: per-row (mean, rstd)

    const int tid  = threadIdx.x;
    const int w    = tid >> 6;
    const int ln   = tid & 63;
    const int lh   = ln >> 5;
    const int l31  = ln & 31;
    const int row0 = blockIdx.x * 32;
    const int n0   = 32 * w + l31;          // L1/L2 col
    const int cg3  = w & 3;
    const int n3   = 32 * cg3 + l31;        // L3 col (waves 0..3)

    _Float16* hh = (_Float16*)hA;
    _Float16* xh = (_Float16*)xA;

    // ---------------- init staging ----------------
    {   // state -> hA split: 512 threads, 32 rows x 16 col-groups of 16
        int m = tid & 31, kb = (tid >> 5) * 16;
        const float4* sp = (const float4*)(state + (size_t)(row0 + m) * SD + kb);
        int base = m * 268 + (kb >> 1);
        #pragma unroll
        for (int q = 0; q < 4; ++q) {
            float4 v = sp[q];
            _Float16 h0 = (_Float16)v.x, h1 = (_Float16)v.y,
                     h2 = (_Float16)v.z, h3 = (_Float16)v.w;
            *(v2h*)(hA + base + 2 * q)     = (v2h){h0, h1};
            *(v2h*)(hA + base + 2 * q + 1) = (v2h){h2, h3};
            *(v2h*)(hA + base + 128 + 2 * q) =
                (v2h){(_Float16)((v.x - (float)h0) * LOSCALE),
                      (_Float16)((v.y - (float)h1) * LOSCALE)};
            *(v2h*)(hA + base + 128 + 2 * q + 1) =
                (v2h){(_Float16)((v.z - (float)h2) * LOSCALE),
                      (_Float16)((v.w - (float)h3) * LOSCALE)};
        }
    }
    if (tid < 256) {   // x_init (+t at 129, zeros 130..143) -> xA split; 32 rows x 8 groups of 18
        int m = tid & 31, k0 = (tid >> 5) * 18;
        float vv[18];
        #pragma unroll
        for (int j = 0; j < 18; ++j) {
            int k = k0 + j;
            vv[j] = (k < AD) ? x_init[(size_t)(row0 + m) * AD + k]
                             : ((k == AD) ? (float)(NSTEP - 1) : 0.f);
        }
        int base = m * 148 + (k0 >> 1);
        #pragma unroll
        for (int j = 0; j < 9; ++j) {
            float a = vv[2 * j], b = vv[2 * j + 1];
            _Float16 ha = (_Float16)a, hb2 = (_Float16)b;
            *(v2h*)(xA + base + j)      = (v2h){ha, hb2};
            *(v2h*)(xA + base + 72 + j) =
                (v2h){(_Float16)((a - (float)ha) * LOSCALE),
                      (_Float16)((b - (float)hb2) * LOSCALE)};
        }
    }
    __syncthreads();

    const float b1n = b1[n0], g1n = g1[n0], e1n = be1[n0];
    const float b2n = b2[n0], g2n = g2[n0], e2n = be2[n0];
    const float b3n = b3[n3], b3c = b3[128];
    const float4 wc4 = *(const float4*)(w3cg + 4 * ln);   // W3 col-128, 4 k's per lane

    // x col 128 lives in waves 4..7: lane i (<8) of wave 4+j owns row 8j+i
    float x128 = (w >= 4 && ln < 8)
               ? x_init[(size_t)(row0 + 8 * (w - 4) + ln) * AD + 128] : 0.f;

    // fragment-packed weight base pointers (v8h units)
    const v8h* P1 = (const v8h*)T1p + (size_t)w * 26 * 2 * 64 + ln;
    const v8h* P2 = (const v8h*)T2p + (size_t)w * 16 * 2 * 64 + ln;
    const v8h* P3 = (const v8h*)T3p + (size_t)cg3 * 16 * 2 * 64 + ln;

    // A-fragment LDS bases (dwords)
    const int a0h = l31 * 268 + lh * 4;
    const int x0h = l31 * 148 + lh * 4;

    // LN + ReLU + split-store to hA. va rows ra=(r&3)+8(r>>2)+4lh, col n0.
    auto ln_store = [&](v16f va, float gn, float bn) {
        #pragma unroll
        for (int r = 0; r < 16; ++r) {
            int ra = (r & 3) + 8 * (r >> 2) + 4 * lh;
            float s0 = allred16(va[r]);
            float q0 = allred16(va[r] * va[r]);
            if ((ln & 15) == 0) {           // lanes 0,16,32,48: one 16-col partial each
                int g = (ln >> 4) & 1;
                lnp[w][g][ra] = make_float2(s0, q0);
            }
        }
        __syncthreads();   // partials ready; also: all waves done reading hA/xA in GEMM
        {   // lane lr combines 16 partials for row lr; broadcast via lnstat
            int lr = ln & 31;
            float S = 0.f, Q = 0.f;
            #pragma unroll
            for (int j = 0; j < 8; ++j) {
                float2 pa = lnp[j][0][lr], pb = lnp[j][1][lr];
                S += pa.x + pb.x; Q += pa.y + pb.y;
            }
            float mean = S * (1.f / 256.f);
            float rstd = rsqrtf(Q * (1.f / 256.f) - mean * mean + EPS_LN);
            lnstat[lr] = make_float2(mean, rstd);   // identical value from every writer
        }
        #pragma unroll
        for (int rq = 0; rq < 4; ++rq) {
            int rb = 8 * rq + 4 * lh;
            float4 s0v = *(const float4*)&lnstat[rb];
            float4 s1v = *(const float4*)&lnstat[rb + 2];
            float ma[4] = {s0v.x, s0v.z, s1v.x, s1v.z};
            float rs[4] = {s0v.y, s0v.w, s1v.y, s1v.w};
            #pragma unroll
            for (int i = 0; i < 4; ++i) {
                int r = 4 * rq + i, ra = rb + i;
                float h0 = fmaxf((va[r] - ma[i]) * rs[i] * gn + bn, 0.f);
                _Float16 c0 = (_Float16)h0;
                hh[ra * 536 + n0]       = c0;
                hh[ra * 536 + 256 + n0] = (_Float16)((h0 - (float)c0) * LOSCALE);
            }
        }
        __syncthreads();   // hA complete (and lnp/lnstat safe for next call)
    };

    // ---------------- pre = b1 + state @ W1[0:256,:] ----------------
    v16f prea;
    {
        v16f c1 = vzero(), c2 = vzero();
        gemm1<16>(P1, 0, hA, a0h, 128, c1, c2);
        prea = c1 + LOINV * c2 + b1n;
    }

    // ---------------- diffusion steps ----------------
    #pragma unroll 1
    for (int s = 0; s < NSTEP; ++s) {
        {   // layer 1: [x;t] @ W1[256:,:] + pre  (K=144 padded, tiles 16..24)
            v16f c1 = vzero(), c2 = vzero();
            gemm1<9>(P1, 16, xA, x0h, 72, c1, c2);
            v16f va = c1 + LOINV * c2 + prea;
            ln_store(va, g1n, e1n);
        }
        {   // layer 2
            v16f c1 = vzero(), c2 = vzero();
            gemm1<16>(P2, 0, hA, a0h, 128, c1, c2);
            v16f va = c1 + LOINV * c2 + b2n;
            ln_store(va, g2n, e2n);
        }
        {   // layer 3: waves 0..3 GEMM + x update; waves 4..7 col-128 concurrently
            if (w < 4) {
                v16f c1 = vzero(), c2 = vzero();
                gemm1<16>(P3, 0, hA, a0h, 128, c1, c2);
                #pragma unroll
                for (int r = 0; r < 16; ++r) {
                    int ra = (r & 3) + 8 * (r >> 2) + 4 * lh;
                    float np = (c1[r] + LOINV * c2[r]) + b3n;
                    float xo = (float)xh[ra * 296 + n3]
                             + LOINV * (float)xh[ra * 296 + 144 + n3];
                    float xn = xo - 0.1f * np;
                    _Float16 h0 = (_Float16)xn;
                    xh[ra * 296 + n3]       = h0;
                    xh[ra * 296 + 144 + n3] = (_Float16)((xn - (float)h0) * LOSCALE);
                }
            } else {
                // col 128 + t col: wave 4+j owns rows 8j..8j+7; lane covers cols 4ln..4ln+3
                float tn = (float)(NSTEP - 2 - s);
                int rbase = 8 * (w - 4);
                #pragma unroll
                for (int i = 0; i < 8; ++i) {
                    int m = rbase + i;
                    const int* hp = hA + m * 268 + 2 * ln;
                    int2 hi4 = *(const int2*)hp;
                    int2 lo4 = *(const int2*)(hp + 128);
                    v2h h01 = __builtin_bit_cast(v2h, hi4.x);
                    v2h h23 = __builtin_bit_cast(v2h, hi4.y);
                    v2h l01 = __builtin_bit_cast(v2h, lo4.x);
                    v2h l23 = __builtin_bit_cast(v2h, lo4.y);
                    float p;
                    p = ((float)h01[0] + LOINV * (float)l01[0]) * wc4.x;
                    p = fmaf((float)h01[1] + LOINV * (float)l01[1], wc4.y, p);
                    p = fmaf((float)h23[0] + LOINV * (float)l23[0], wc4.z, p);
                    p = fmaf((float)h23[1] + LOINV * (float)l23[1], wc4.w, p);
                    p = allred16(p);
                    p += __shfl_xor(p, 16);
                    p += __shfl_xor(p, 32);
                    if (ln == i) {
                        x128 = x128 - 0.1f * (p + b3c);
                        _Float16 hx = (_Float16)x128;
                        *(v2h*)(xh + m * 296 + 128) = (v2h){hx, (_Float16)tn};
                        *(v2h*)(xh + m * 296 + 144 + 128) =
                            (v2h){(_Float16)((x128 - (float)hx) * LOSCALE), (_Float16)0.f};
                    }
                }
            }
            __syncthreads();
        }
    }

    // ---------------- finale: masked gumbel softmax + tanh ----------------
    {
        float xv[8];   // 4 rows x 2 cols per lane
        #pragma unroll
        for (int c = 0; c < 2; ++c) {
            int col = 2 * ln + c;
            #pragma unroll
            for (int r = 0; r < 4; ++r) {
                int m = 4 * w + r;
                xv[r * 2 + c] = (float)xh[m * 296 + col]
                              + LOINV * (float)xh[m * 296 + 144 + col];
            }
        }
        float lg[8];
        #pragma unroll
        for (int r = 0; r < 4; ++r) {
            size_t grow = (size_t)(row0 + 4 * w + r);
            float2 mv = *(const float2*)&amask[grow * 128 + 2 * ln];
            float2 gv = *(const float2*)&gum  [grow * 128 + 2 * ln];
            lg[r * 2 + 0] = xv[r * 2 + 0] + (1.f - mv.x) * -1e9f + gv.x;
            lg[r * 2 + 1] = xv[r * 2 + 1] + (1.f - mv.y) * -1e9f + gv.y;
        }
        float mx[4];
        #pragma unroll
        for (int r = 0; r < 4; ++r) mx[r] = fmaxf(lg[r * 2], lg[r * 2 + 1]);
        wr_max<4>(mx);
        float es[8], sum[4];
        #pragma unroll
        for (int r = 0; r < 4; ++r) {
            es[r * 2 + 0] = expf(lg[r * 2 + 0] - mx[r]);
            es[r * 2 + 1] = expf(lg[r * 2 + 1] - mx[r]);
            sum[r] = es[r * 2 + 0] + es[r * 2 + 1];
        }
        wr_add<4>(sum);
        float soft[8], sm[4];
        #pragma unroll
        for (int r = 0; r < 4; ++r) {
            soft[r * 2 + 0] = es[r * 2 + 0] / sum[r];
            soft[r * 2 + 1] = es[r * 2 + 1] / sum[r];
            sm[r] = fmaxf(soft[r * 2 + 0], soft[r * 2 + 1]);
        }
        wr_max<4>(sm);
        int idx[4];
        #pragma unroll
        for (int r = 0; r < 4; ++r) {
            idx[r] = (soft[r * 2 + 0] == sm[r]) ? (2 * ln)
                   : ((soft[r * 2 + 1] == sm[r]) ? (2 * ln + 1) : 0x7fffffff);
        }
        wr_mini<4>(idx);
        #pragma unroll
        for (int r = 0; r < 4; ++r) {
            size_t grow = (size_t)(row0 + 4 * w + r);
            float* orow = out + grow * AD;
            float h0 = (2 * ln + 0 == idx[r]) ? 1.f : 0.f;
            float h1 = (2 * ln + 1 == idx[r]) ? 1.f : 0.f;
            orow[2 * ln + 0] = h0 + soft[r * 2 + 0] - soft[r * 2 + 0];
            orow[2 * ln + 1] = h1 + soft[r * 2 + 1] - soft[r * 2 + 1];
        }
        if (ln == 0) {
            #pragma unroll
            for (int r = 0; r < 4; ++r) {
                int m = 4 * w + r;
                float sv = (float)xh[m * 296 + 128] + LOINV * (float)xh[m * 296 + 144 + 128];
                out[(size_t)(row0 + m) * AD + 128] = tanhf(sv);
            }
        }
    }
}

extern "C" void kernel_launch(void* const* d_in, const int* in_sizes, int n_in,
                              void* d_out, int out_size, void* d_ws, size_t ws_size,
                              hipStream_t stream) {
    const float* state  = (const float*)d_in[0];
    const float* amask  = (const float*)d_in[1];
    const float* x_init = (const float*)d_in[2];
    const float* gum    = (const float*)d_in[3];
    const float* W1     = (const float*)d_in[4];
    const float* b1     = (const float*)d_in[5];
    const float* g1     = (const float*)d_in[6];
    const float* be1    = (const float*)d_in[7];
    const float* W2     = (const float*)d_in[8];
    const float* b2     = (const float*)d_in[9];
    const float* g2     = (const float*)d_in[10];
    const float* be2    = (const float*)d_in[11];
    const float* W3     = (const float*)d_in[12];
    const float* b3     = (const float*)d_in[13];
    float* out = (float*)d_out;
    char*  ws  = (char*)d_ws;

    hipLaunchKernelGGL(repack, dim3(401), dim3(128), 0, stream, W1, W2, W3, ws);
    hipLaunchKernelGGL(actor_kernel, dim3(BATCH / 32), dim3(512), 0, stream,
                       state, amask, x_init, gum,
                       b1, g1, be1, b2, g2, be2, b3,
                       (const _Float16*)(ws + T1P_OFF), (const _Float16*)(ws + T2P_OFF),
                       (const _Float16*)(ws + T3P_OFF), (const float*)(ws + W3C_OFF), out);
}

// Round 10
// 2415.571 us; speedup vs baseline: 1.2641x; 1.2641x over previous
//
#include <hip/hip_runtime.h>
#include <math.h>

#define BATCH  65536
#define SD     256
#define AD     129
#define HID    256
#define NSTEP  30
#define EPS_LN 1e-5f

typedef _Float16 v8h  __attribute__((ext_vector_type(8)));
typedef _Float16 v2h  __attribute__((ext_vector_type(2)));
typedef float    v16f __attribute__((ext_vector_type(16)));

#define LOSCALE 4096.0f
#define LOINV   (1.0f/4096.0f)
#define MFMA(a,b,c) __builtin_amdgcn_mfma_f32_32x32x16_f16(a,b,c,0,0,0)

// d_ws layout: fragment-packed, fully-coalesced weights.
// packed[cg][t][h][ln][j] = split_h( W[k = 16t + 8*(ln>>5) + j][n = 32cg + (ln&31)] )
#define T1P_OFF 0        // 8 cg * 26 t * 2 * 64 * 16B = 425984
#define T2P_OFF 425984   // 8 cg * 16 t * 2 * 64 * 16B = 262144
#define T3P_OFF 688128   // 4 cg * 16 t * 2 * 64 * 16B = 131072
#define W3C_OFF 819200   // 256 floats (W3 col 128)

__global__ __launch_bounds__(128)
void repack(const float* __restrict__ W1, const float* __restrict__ W2,
            const float* __restrict__ W3, char* __restrict__ ws)
{
    const int b   = blockIdx.x;
    const int tid = threadIdx.x;
    if (b == 400) {   // W3 column 128 -> f32 table
        float* w3c = (float*)(ws + W3C_OFF);
        w3c[tid]       = W3[(size_t)tid * AD + 128];
        w3c[tid + 128] = W3[(size_t)(tid + 128) * AD + 128];
        return;
    }
    const int h = tid >> 6, ln = tid & 63;
    const int lh = ln >> 5, l31 = ln & 31;
    const float* W; _Float16* dst; int cg, t, K, ldw, nt;
    if (b < 208)      { cg = b / 26;         t = b % 26;         W = W1; dst = (_Float16*)(ws + T1P_OFF); K = 386; ldw = HID; nt = 26; }
    else if (b < 336) { cg = (b - 208) / 16; t = (b - 208) % 16; W = W2; dst = (_Float16*)(ws + T2P_OFF); K = 256; ldw = HID; nt = 16; }
    else              { cg = (b - 336) / 16; t = (b - 336) % 16; W = W3; dst = (_Float16*)(ws + T3P_OFF); K = 256; ldw = AD;  nt = 16; }
    const int n = 32 * cg + l31;
    _Float16 frag[8];
    #pragma unroll
    for (int j = 0; j < 8; ++j) {
        int k = 16 * t + 8 * lh + j;
        float v = (k < K) ? W[(size_t)k * ldw + n] : 0.f;
        _Float16 hi = (_Float16)v;
        frag[j] = h ? (_Float16)((v - (float)hi) * LOSCALE) : hi;
    }
    *(v8h*)(dst + ((size_t)((cg * nt + t) * 2 + h) * 64 + ln) * 8) = *(v8h*)frag;
}

__device__ __forceinline__ v16f vzero() {
    v16f z;
    #pragma unroll
    for (int i = 0; i < 16; ++i) z[i] = 0.f;
    return z;
}
// DPP butterfly pieces: quad xor1, quad xor2, row_ror:4, row_ror:8 -> 16-lane allreduce
// bound_ctrl=true (identical semantics here: no disabled lanes) lets the compiler
// fold mov_dpp+add into a single v_add_f32_dpp.
template<int CTRL>
__device__ __forceinline__ float dppadd(float x) {
    union { float f; int i; } a, b;
    a.f = x;
    b.i = __builtin_amdgcn_update_dpp(0, a.i, CTRL, 0xF, 0xF, true);
    return x + b.f;
}
__device__ __forceinline__ float allred16(float x) {
    x = dppadd<0xB1>(x);    // quad_perm [1,0,3,2]  (xor 1)
    x = dppadd<0x4E>(x);    // quad_perm [2,3,0,1]  (xor 2)
    x = dppadd<0x124>(x);   // row_ror:4
    x = dppadd<0x128>(x);   // row_ror:8
    return x;
}
template<int N> __device__ __forceinline__ void wr_add(float* v) {
    #pragma unroll
    for (int d = 1; d < 64; d <<= 1) {
        #pragma unroll
        for (int r = 0; r < N; ++r) v[r] += __shfl_xor(v[r], d);
    }
}
template<int N> __device__ __forceinline__ void wr_max(float* v) {
    #pragma unroll
    for (int d = 1; d < 64; d <<= 1) {
        #pragma unroll
        for (int r = 0; r < N; ++r) v[r] = fmaxf(v[r], __shfl_xor(v[r], d));
    }
}
template<int N> __device__ __forceinline__ void wr_mini(int* v) {
    #pragma unroll
    for (int d = 1; d < 64; d <<= 1) {
        #pragma unroll
        for (int r = 0; r < N; ++r) v[r] = min(v[r], __shfl_xor(v[r], d));
    }
}

// Direct-load GEMM engines (r4-proven): compiler software-pipelines the 4-tile
// unroll groups; no explicit register buffer -> no spill.
template<int NTILE>
__device__ __forceinline__ void gemm2(const v8h* __restrict__ P, int tbase,
    const int* __restrict__ Ab, int a0, int a1, int loff,
    v16f& c1a, v16f& c2a, v16f& c1b, v16f& c2b)
{
    #pragma unroll 4
    for (int t = 0; t < NTILE; ++t) {
        v8h bh  = P[(size_t)(2 * (tbase + t)) * 64];
        v8h bl  = P[(size_t)(2 * (tbase + t) + 1) * 64];
        v8h ah0 = *(const v8h*)(Ab + a0 + 8 * t);
        v8h al0 = *(const v8h*)(Ab + a0 + loff + 8 * t);
        v8h ah1 = *(const v8h*)(Ab + a1 + 8 * t);
        v8h al1 = *(const v8h*)(Ab + a1 + loff + 8 * t);
        c1a = MFMA(ah0, bh, c1a);
        c2a = MFMA(ah0, bl, c2a);
        c2a = MFMA(al0, bh, c2a);
        c1b = MFMA(ah1, bh, c1b);
        c2b = MFMA(ah1, bl, c2b);
        c2b = MFMA(al1, bh, c2b);
    }
}
template<int NTILE>
__device__ __forceinline__ void gemm1(const v8h* __restrict__ P,
    const int* __restrict__ Ab, int a0, int loff,
    v16f& c1, v16f& c2x, v16f& c2y)
{
    #pragma unroll 4
    for (int t = 0; t < NTILE; ++t) {
        v8h bh = P[(size_t)(2 * t) * 64];
        v8h bl = P[(size_t)(2 * t + 1) * 64];
        v8h ah = *(const v8h*)(Ab + a0 + 8 * t);
        v8h al = *(const v8h*)(Ab + a0 + loff + 8 * t);
        c1  = MFMA(ah, bh, c1);
        c2x = MFMA(ah, bl, c2x);
        c2y = MFMA(al, bh, c2y);
    }
}

// M=64 rows/block, 512 threads = 8 waves, 1 block/CU (LDS ~112 KB).
// Layers 1/2: wave w owns all 64 rows x cols [32w, 32w+32).
// Layer 3: wave w owns rows 32*(w>>2)+[0,32) x cols 32*(w&3)+[0,32) with x held
// in fp32 registers (xf); col-128 split 8 rows/wave.
__global__ __launch_bounds__(512, 2)
void actor_kernel(const float* __restrict__ state,
                  const float* __restrict__ amask,
                  const float* __restrict__ x_init,
                  const float* __restrict__ gum,
                  const float* __restrict__ b1,
                  const float* __restrict__ g1,
                  const float* __restrict__ be1,
                  const float* __restrict__ b2,
                  const float* __restrict__ g2,
                  const float* __restrict__ be2,
                  const float* __restrict__ b3,
                  const _Float16* __restrict__ T1p,
                  const _Float16* __restrict__ T2p,
                  const _Float16* __restrict__ T3p,
                  const float* __restrict__ w3cg,
                  float* __restrict__ out)
{
    __shared__ int    hA[64 * 268];            // 68.6 KB
    __shared__ int    xA[64 * 148];            // 37.9 KB
    __shared__ float2 lnp[8][2][64];           // 8 KB: per-colgroup 16-lane partials
    __shared__ __align__(16) float2 lnstat[64]; // 0.5 KB: per-row (mean, rstd)

    const int tid  = threadIdx.x;
    const int w    = tid >> 6;
    const int ln   = tid & 63;
    const int lh   = ln >> 5;
    const int l31  = ln & 31;
    const int row0 = blockIdx.x * 64;
    const int n0   = 32 * w + l31;          // L1/L2 col
    const int n3   = 32 * (w & 3) + l31;    // L3 col
    const int hb   = w >> 2;                // L3 row half

    _Float16* hh = (_Float16*)hA;
    _Float16* xh = (_Float16*)xA;

    // ---------------- init staging ----------------
    {   // state -> hA split
        int m = tid & 63, kb = (tid >> 6) * 32;
        const float4* sp = (const float4*)(state + (size_t)(row0 + m) * SD + kb);
        int base = m * 268 + (kb >> 1);
        #pragma unroll
        for (int q = 0; q < 8; ++q) {
            float4 v = sp[q];
            _Float16 h0 = (_Float16)v.x, h1 = (_Float16)v.y,
                     h2 = (_Float16)v.z, h3 = (_Float16)v.w;
            *(v2h*)(hA + base + 2 * q)     = (v2h){h0, h1};
            *(v2h*)(hA + base + 2 * q + 1) = (v2h){h2, h3};
            *(v2h*)(hA + base + 128 + 2 * q) =
                (v2h){(_Float16)((v.x - (float)h0) * LOSCALE),
                      (_Float16)((v.y - (float)h1) * LOSCALE)};
            *(v2h*)(hA + base + 128 + 2 * q + 1) =
                (v2h){(_Float16)((v.z - (float)h2) * LOSCALE),
                      (_Float16)((v.w - (float)h3) * LOSCALE)};
        }
    }
    {   // x_init (+t at 129, zeros 130..143) -> xA split
        int m = tid & 63, k0 = (tid >> 6) * 18;
        float vv[18];
        #pragma unroll
        for (int j = 0; j < 18; ++j) {
            int k = k0 + j;
            vv[j] = (k < AD) ? x_init[(size_t)(row0 + m) * AD + k]
                             : ((k == AD) ? (float)(NSTEP - 1) : 0.f);
        }
        int base = m * 148 + (k0 >> 1);
        #pragma unroll
        for (int j = 0; j < 9; ++j) {
            float a = vv[2 * j], b = vv[2 * j + 1];
            _Float16 ha = (_Float16)a, hb2 = (_Float16)b;
            *(v2h*)(xA + base + j)      = (v2h){ha, hb2};
            *(v2h*)(xA + base + 72 + j) =
                (v2h){(_Float16)((a - (float)ha) * LOSCALE),
                      (_Float16)((b - (float)hb2) * LOSCALE)};
        }
    }
    __syncthreads();

    const float b1n = b1[n0], g1n = g1[n0], e1n = be1[n0];
    const float b2n = b2[n0], g2n = g2[n0], e2n = be2[n0];
    const float b3n = b3[n3], b3c = b3[128];
    const float4 wc4 = *(const float4*)(w3cg + 4 * ln);   // W3 col-128, 4 k's per lane

    // fp32 x state for this wave's L3 tile: rows ra+32*hb, col n3
    float xf[16];
    #pragma unroll
    for (int r = 0; r < 16; ++r) {
        int ra = (r & 3) + 8 * (r >> 2) + 4 * lh + 32 * hb;
        xf[r] = x_init[(size_t)(row0 + ra) * AD + n3];
    }
    // x col 128: lane i (<8) of wave w owns row 8w+i
    float x128 = (ln < 8) ? x_init[(size_t)(row0 + 8 * w + ln) * AD + 128] : 0.f;

    // fragment-packed weight base pointers (v8h units)
    const v8h* P1 = (const v8h*)T1p + (size_t)w * 26 * 2 * 64 + ln;
    const v8h* P2 = (const v8h*)T2p + (size_t)w * 16 * 2 * 64 + ln;
    const v8h* P3 = (const v8h*)T3p + (size_t)(w & 3) * 16 * 2 * 64 + ln;

    // A-fragment LDS bases (dwords)
    const int a0h = l31 * 268 + lh * 4;
    const int a1h = (l31 + 32) * 268 + lh * 4;
    const int a3h = (32 * hb + l31) * 268 + lh * 4;
    const int x0h = l31 * 148 + lh * 4;
    const int x1h = (l31 + 32) * 148 + lh * 4;

    // LN + ReLU + split-store to hA. va rows ra=(r&3)+8(r>>2)+4lh, vb rows +32, col n0.
    auto ln_store = [&](v16f va, v16f vb, float gn, float bn) {
        #pragma unroll
        for (int r = 0; r < 16; ++r) {
            int ra = (r & 3) + 8 * (r >> 2) + 4 * lh;
            float s0 = allred16(va[r]);
            float q0 = allred16(va[r] * va[r]);
            float s1 = allred16(vb[r]);
            float q1 = allred16(vb[r] * vb[r]);
            if ((ln & 15) == 0) {           // lanes 0,16,32,48: one 16-group partial each
                int g = (ln >> 4) & 1;
                lnp[w][g][ra]      = make_float2(s0, q0);
                lnp[w][g][ra + 32] = make_float2(s1, q1);
            }
        }
        __syncthreads();   // partials ready; also: all waves done reading hA/xA in GEMM
        {   // lane ln combines 16 partials for row ln; broadcast via lnstat
            float S = 0.f, Q = 0.f;
            #pragma unroll
            for (int j = 0; j < 8; ++j) {
                float2 pa = lnp[j][0][ln], pb = lnp[j][1][ln];
                S += pa.x + pb.x; Q += pa.y + pb.y;
            }
            float mean = S * (1.f / 256.f);
            float rstd = rsqrtf(Q * (1.f / 256.f) - mean * mean + EPS_LN);
            lnstat[ln] = make_float2(mean, rstd);   // identical value from every wave
        }
        #pragma unroll
        for (int rq = 0; rq < 4; ++rq) {
            int rb = 8 * rq + 4 * lh;
            float4 sA0 = *(const float4*)&lnstat[rb];        // rows rb, rb+1
            float4 sA1 = *(const float4*)&lnstat[rb + 2];
            float4 sB0 = *(const float4*)&lnstat[rb + 32];
            float4 sB1 = *(const float4*)&lnstat[rb + 34];
            float maA[4] = {sA0.x, sA0.z, sA1.x, sA1.z};
            float rsA[4] = {sA0.y, sA0.w, sA1.y, sA1.w};
            float maB[4] = {sB0.x, sB0.z, sB1.x, sB1.z};
            float rsB[4] = {sB0.y, sB0.w, sB1.y, sB1.w};
            #pragma unroll
            for (int i = 0; i < 4; ++i) {
                int r = 4 * rq + i, ra = rb + i;
                float h0 = fmaxf((va[r] - maA[i]) * rsA[i] * gn + bn, 0.f);
                float h1 = fmaxf((vb[r] - maB[i]) * rsB[i] * gn + bn, 0.f);
                _Float16 c0 = (_Float16)h0, c1 = (_Float16)h1;
                hh[ra * 536 + n0]              = c0;
                hh[ra * 536 + 256 + n0]        = (_Float16)((h0 - (float)c0) * LOSCALE);
                hh[(ra + 32) * 536 + n0]       = c1;
                hh[(ra + 32) * 536 + 256 + n0] = (_Float16)((h1 - (float)c1) * LOSCALE);
            }
        }
        __syncthreads();   // hA complete (and lnp/lnstat safe for next call)
    };

    // ---------------- pre = b1 + state @ W1[0:256,:] ----------------
    v16f prea, preb;
    {
        v16f c1a = vzero(), c2a = vzero(), c1b = vzero(), c2b = vzero();
        gemm2<16>(P1, 0, hA, a0h, a1h, 128, c1a, c2a, c1b, c2b);
        prea = c1a + LOINV * c2a + b1n;
        preb = c1b + LOINV * c2b + b1n;
    }

    // ---------------- diffusion steps ----------------
    #pragma unroll 1
    for (int s = 0; s < NSTEP; ++s) {
        {   // layer 1: [x;t] @ W1[256:,:] + pre  (K=144 padded, tiles 16..24)
            v16f c1a = vzero(), c2a = vzero(), c1b = vzero(), c2b = vzero();
            gemm2<9>(P1, 16, xA, x0h, x1h, 72, c1a, c2a, c1b, c2b);
            v16f va = c1a + LOINV * c2a + prea;
            v16f vb = c1b + LOINV * c2b + preb;
            ln_store(va, vb, g1n, e1n);
        }
        {   // layer 2
            v16f c1a = vzero(), c2a = vzero(), c1b = vzero(), c2b = vzero();
            gemm2<16>(P2, 0, hA, a0h, a1h, 128, c1a, c2a, c1b, c2b);
            v16f va = c1a + LOINV * c2a + b2n;
            v16f vb = c1b + LOINV * c2b + b2n;
            ln_store(va, vb, g2n, e2n);
        }
        {   // layer 3 (balanced: every wave 48 MFMA + 8 col-128 rows) + x update
            v16f c1 = vzero(), c2x = vzero(), c2y = vzero();
            gemm1<16>(P3, hA, a3h, 128, c1, c2x, c2y);
            #pragma unroll
            for (int r = 0; r < 16; ++r) {
                int ra = (r & 3) + 8 * (r >> 2) + 4 * lh + 32 * hb;
                float np = (c1[r] + LOINV * (c2x[r] + c2y[r])) + b3n;
                float xn = xf[r] - 0.1f * np;
                xf[r] = xn;
                _Float16 h0 = (_Float16)xn;
                xh[ra * 296 + n3]       = h0;
                xh[ra * 296 + 144 + n3] = (_Float16)((xn - (float)h0) * LOSCALE);
            }
            // col 128 + t col: wave w owns rows 8w..8w+7; lane covers cols 4ln..4ln+3
            float tn = (float)(NSTEP - 2 - s);
            #pragma unroll
            for (int i = 0; i < 8; ++i) {
                int m = 8 * w + i;
                const int* hp = hA + m * 268 + 2 * ln;
                int2 hi4 = *(const int2*)hp;
                int2 lo4 = *(const int2*)(hp + 128);
                v2h h01 = __builtin_bit_cast(v2h, hi4.x);
                v2h h23 = __builtin_bit_cast(v2h, hi4.y);
                v2h l01 = __builtin_bit_cast(v2h, lo4.x);
                v2h l23 = __builtin_bit_cast(v2h, lo4.y);
                float p;
                p = ((float)h01[0] + LOINV * (float)l01[0]) * wc4.x;
                p = fmaf((float)h01[1] + LOINV * (float)l01[1], wc4.y, p);
                p = fmaf((float)h23[0] + LOINV * (float)l23[0], wc4.z, p);
                p = fmaf((float)h23[1] + LOINV * (float)l23[1], wc4.w, p);
                p = allred16(p);
                p += __shfl_xor(p, 16);
                p += __shfl_xor(p, 32);
                if (ln == i) {
                    x128 = x128 - 0.1f * (p + b3c);
                    _Float16 hx = (_Float16)x128;
                    *(v2h*)(xh + m * 296 + 128) = (v2h){hx, (_Float16)tn};
                    *(v2h*)(xh + m * 296 + 144 + 128) =
                        (v2h){(_Float16)((x128 - (float)hx) * LOSCALE), (_Float16)0.f};
                }
            }
            __syncthreads();
        }
    }

    // ---------------- finale: masked gumbel softmax + tanh ----------------
    {
        float xv[16];
        #pragma unroll
        for (int c = 0; c < 2; ++c) {
            int col = 2 * ln + c;
            #pragma unroll
            for (int r = 0; r < 8; ++r) {
                int m = 8 * w + r;
                xv[r * 2 + c] = (float)xh[m * 296 + col]
                              + LOINV * (float)xh[m * 296 + 144 + col];
            }
        }
        float lg[16];
        #pragma unroll
        for (int r = 0; r < 8; ++r) {
            size_t grow = (size_t)(row0 + 8 * w + r);
            float2 mv = *(const float2*)&amask[grow * 128 + 2 * ln];
            float2 gv = *(const float2*)&gum  [grow * 128 + 2 * ln];
            lg[r * 2 + 0] = xv[r * 2 + 0] + (1.f - mv.x) * -1e9f + gv.x;
            lg[r * 2 + 1] = xv[r * 2 + 1] + (1.f - mv.y) * -1e9f + gv.y;
        }
        float mx[8];
        #pragma unroll
        for (int r = 0; r < 8; ++r) mx[r] = fmaxf(lg[r * 2], lg[r * 2 + 1]);
        wr_max<8>(mx);
        float es[16], sum[8];
        #pragma unroll
        for (int r = 0; r < 8; ++r) {
            es[r * 2 + 0] = expf(lg[r * 2 + 0] - mx[r]);
            es[r * 2 + 1] = expf(lg[r * 2 + 1] - mx[r]);
            sum[r] = es[r * 2 + 0] + es[r * 2 + 1];
        }
        wr_add<8>(sum);
        float soft[16], sm[8];
        #pragma unroll
        for (int r = 0; r < 8; ++r) {
            soft[r * 2 + 0] = es[r * 2 + 0] / sum[r];
            soft[r * 2 + 1] = es[r * 2 + 1] / sum[r];
            sm[r] = fmaxf(soft[r * 2 + 0], soft[r * 2 + 1]);
        }
        wr_max<8>(sm);
        int idx[8];
        #pragma unroll
        for (int r = 0; r < 8; ++r) {
            idx[r] = (soft[r * 2 + 0] == sm[r]) ? (2 * ln)
                   : ((soft[r * 2 + 1] == sm[r]) ? (2 * ln + 1) : 0x7fffffff);
        }
        wr_mini<8>(idx);
        #pragma unroll
        for (int r = 0; r < 8; ++r) {
            size_t grow = (size_t)(row0 + 8 * w + r);
            float* orow = out + grow * AD;
            float h0 = (2 * ln + 0 == idx[r]) ? 1.f : 0.f;
            float h1 = (2 * ln + 1 == idx[r]) ? 1.f : 0.f;
            orow[2 * ln + 0] = h0 + soft[r * 2 + 0] - soft[r * 2 + 0];
            orow[2 * ln + 1] = h1 + soft[r * 2 + 1] - soft[r * 2 + 1];
        }
        if (ln == 0) {
            #pragma unroll
            for (int r = 0; r < 8; ++r) {
                int m = 8 * w + r;
                float sv = (float)xh[m * 296 + 128] + LOINV * (float)xh[m * 296 + 144 + 128];
                out[(size_t)(row0 + m) * AD + 128] = tanhf(sv);
            }
        }
    }
}

extern "C" void kernel_launch(void* const* d_in, const int* in_sizes, int n_in,
                              void* d_out, int out_size, void* d_ws, size_t ws_size,
                              hipStream_t stream) {
    const float* state  = (const float*)d_in[0];
    const float* amask  = (const float*)d_in[1];
    const float* x_init = (const float*)d_in[2];
    const float* gum    = (const float*)d_in[3];
    const float* W1     = (const float*)d_in[4];
    const float* b1     = (const float*)d_in[5];
    const float* g1     = (const float*)d_in[6];
    const float* be1    = (const float*)d_in[7];
    const float* W2     = (const float*)d_in[8];
    const float* b2     = (const float*)d_in[9];
    const float* g2     = (const float*)d_in[10];
    const float* be2    = (const float*)d_in[11];
    const float* W3     = (const float*)d_in[12];
    const float* b3     = (const float*)d_in[13];
    float* out = (float*)d_out;
    char*  ws  = (char*)d_ws;

    hipLaunchKernelGGL(repack, dim3(401), dim3(128), 0, stream, W1, W2, W3, ws);
    hipLaunchKernelGGL(actor_kernel, dim3(BATCH / 64), dim3(512), 0, stream,
                       state, amask, x_init, gum,
                       b1, g1, be1, b2, g2, be2, b3,
                       (const _Float16*)(ws + T1P_OFF), (const _Float16*)(ws + T2P_OFF),
                       (const _Float16*)(ws + T3P_OFF), (const float*)(ws + W3C_OFF), out);
}